// Round 9
// baseline (190.729 us; speedup 1.0000x reference)
//
#include <hip/hip_runtime.h>
#include <stdint.h>

// BertSelfAttentionWithRelation  B=4 L=512 H=12 D=64 HIDDEN=768
// Round 9: occupancy/tail/latency fixes on the R8 structure.
//   k_relv: rc 4->8 (64 r/block), PS 24KB, 2-deep pipeline, bounds(256,3)
//           -> 3 blocks/CU, 1024 blocks (4 scheduling rounds)
//   k_relA: Sb content values prefetched via counted global_load_ushort
//           behind the relk tile queue (no serial post-barrier L3 stalls)
//   part: 8 bf16 planes (overlay on dead Sb region)

typedef __attribute__((ext_vector_type(8))) short bf16x8;
typedef __attribute__((ext_vector_type(4))) float f32x4;
typedef __attribute__((ext_vector_type(4))) unsigned int u32x4;
typedef __attribute__((ext_vector_type(2))) unsigned int u32x2;

__device__ __forceinline__ unsigned short f2bf(float f) {
  union { float f; unsigned int u; } v; v.f = f;
  unsigned int r = v.u + 0x7fffu + ((v.u >> 16) & 1u);
  return (unsigned short)(r >> 16);
}
__device__ __forceinline__ float bf2f(unsigned short s) {
  union { unsigned int u; float f; } v; v.u = ((unsigned int)s) << 16;
  return v.f;
}
__device__ __forceinline__ float ubf(unsigned u) {   // low 16 bits = bf16
  union { unsigned int u; float f; } v; v.u = u << 16;
  return v.f;
}
__device__ __forceinline__ void lds_barrier() {
  asm volatile("s_waitcnt lgkmcnt(0)\ns_barrier" ::: "memory");
}
__device__ __forceinline__ unsigned cvtpk(float lo, float hi) {
  unsigned r;
  asm("v_cvt_pk_bf16_f32 %0, %1, %2" : "=v"(r) : "v"(lo), "v"(hi));
  return r;
}

#define GL16(dst, addr, OFF)                                                  \
  asm volatile("global_load_dwordx4 %0, %1, off offset:" #OFF                \
               : "=v"(dst) : "v"(addr))
#define GLU(dst, addr, OFF)                                                   \
  asm volatile("global_load_ushort %0, %1, off offset:" #OFF                 \
               : "=v"(dst) : "v"(addr))
#define WAITV(N)                                                              \
  do {                                                                        \
    asm volatile("s_waitcnt vmcnt(" #N ")" ::: "memory");                     \
    __builtin_amdgcn_sched_barrier(0);                                        \
  } while (0)

// ---------------- K0a: hidden fp32 -> bf16 ----------------
__global__ void k_cvt_hidden(const float* __restrict__ x, unsigned short* __restrict__ y) {
  int i = blockIdx.x * 256 + threadIdx.x;
  float4 v = reinterpret_cast<const float4*>(x)[i];
  ushort4 o;
  o.x = f2bf(v.x); o.y = f2bf(v.y); o.z = f2bf(v.z); o.w = f2bf(v.w);
  reinterpret_cast<ushort4*>(y)[i] = o;
}

// ---------------- K0b: W -> W^T concat bf16 ----------------
__global__ void k_transp_w(const float* __restrict__ Wq, const float* __restrict__ Wk,
                           const float* __restrict__ Wv, unsigned short* __restrict__ wt) {
  __shared__ float t[64][65];
  const int kt = blockIdx.x, nt = blockIdx.y, wsel = blockIdx.z;
  const float* W = wsel == 0 ? Wq : (wsel == 1 ? Wk : Wv);
  const int lx = threadIdx.x & 63, ly = threadIdx.x >> 6;
  for (int i = 0; i < 64; i += 4)
    t[ly + i][lx] = W[(size_t)(kt * 64 + ly + i) * 768 + nt * 64 + lx];
  __syncthreads();
  for (int i = 0; i < 64; i += 4) {
    int r = ly + i;
    wt[((size_t)wsel * 768 + nt * 64 + r) * 768 + kt * 64 + lx] = f2bf(t[lx][r]);
  }
}

// ---------------- K1: fused QKV GEMM (bf16 MFMA) ----------------
__global__ __launch_bounds__(256) void k_qkv_gemm(
    const unsigned short* __restrict__ A, const unsigned short* __restrict__ Bt,
    const float* __restrict__ bq, const float* __restrict__ bk, const float* __restrict__ bv,
    unsigned short* __restrict__ qbf, unsigned short* __restrict__ kbf,
    unsigned short* __restrict__ vbt) {
  __shared__ __align__(16) unsigned short lA[64 * 64];
  __shared__ __align__(16) unsigned short lB[64 * 64];
  const int tid = threadIdx.x, lane = tid & 63, w = tid >> 6;
  const int m0 = blockIdx.x * 64, n0 = blockIdx.y * 64;
  const int wm = (w >> 1) * 32, wn = (w & 1) * 32;
  f32x4 acc[2][2] = {};

  for (int kt = 0; kt < 12; ++kt) {
    __syncthreads();
#pragma unroll
    for (int i = 0; i < 2; ++i) {
      int e16 = i * 256 + tid;
      int row = e16 >> 3;
      int kb = (e16 & 7) * 16;
      int dst = row * 128 + (kb ^ ((row & 7) << 4));
      u32x4 va = *(const u32x4*)((const char*)A + (size_t)(m0 + row) * 1536 + kt * 128 + kb);
      *(u32x4*)((char*)lA + dst) = va;
      u32x4 vb = *(const u32x4*)((const char*)Bt + (size_t)(n0 + row) * 1536 + kt * 128 + kb);
      *(u32x4*)((char*)lB + dst) = vb;
    }
    __syncthreads();
#pragma unroll
    for (int ks = 0; ks < 2; ++ks) {
      bf16x8 fa[2], fb[2];
      const int kbyte = (ks * 32 + (lane >> 4) * 8) * 2;
#pragma unroll
      for (int mi = 0; mi < 2; ++mi) {
        int row = wm + mi * 16 + (lane & 15);
        fa[mi] = *(const bf16x8*)((const char*)lA + row * 128 + (kbyte ^ ((row & 7) << 4)));
      }
#pragma unroll
      for (int ni = 0; ni < 2; ++ni) {
        int row = wn + ni * 16 + (lane & 15);
        fb[ni] = *(const bf16x8*)((const char*)lB + row * 128 + (kbyte ^ ((row & 7) << 4)));
      }
#pragma unroll
      for (int mi = 0; mi < 2; ++mi)
#pragma unroll
        for (int ni = 0; ni < 2; ++ni)
          acc[mi][ni] = __builtin_amdgcn_mfma_f32_16x16x32_bf16(fa[mi], fb[ni], acc[mi][ni], 0, 0, 0);
    }
  }
#pragma unroll
  for (int mi = 0; mi < 2; ++mi)
#pragma unroll
    for (int ni = 0; ni < 2; ++ni) {
      int gn = n0 + wn + ni * 16 + (lane & 15);
      float bias = (gn < 768) ? bq[gn] : (gn < 1536 ? bk[gn - 768] : bv[gn - 1536]);
#pragma unroll
      for (int r = 0; r < 4; ++r) {
        int gm = m0 + wm + mi * 16 + ((lane >> 4) << 2) + r;
        float val = acc[mi][ni][r] + bias;
        int b = gm >> 9, l = gm & 511;
        int d = gn & 63;
        if (gn < 768) {
          int h = gn >> 6;
          qbf[(((size_t)(b * 12 + h)) * 512 + l) * 64 + d] = f2bf(val);
        } else if (gn < 1536) {
          int h = (gn - 768) >> 6;
          kbf[(((size_t)(b * 12 + h)) * 512 + l) * 64 + d] = f2bf(val);
        } else {
          int h = (gn - 1536) >> 6;
          vbt[(((size_t)(b * 12 + h)) * 64 + d) * 512 + l] = f2bf(val);
        }
      }
    }
}

// ---------------- K2a: content scores S = q.k^T per (b,h), bf16 out -------
__global__ __launch_bounds__(256) void k_scores(
    const unsigned short* __restrict__ qbf, const unsigned short* __restrict__ kbf,
    unsigned short* __restrict__ Sb) {
  __shared__ __align__(16) unsigned short lQ[64 * 64];
  __shared__ __align__(16) unsigned short lK[64 * 64];
  const int tid = threadIdx.x, lane = tid & 63, w = tid >> 6;
  const int mt = blockIdx.x, lt = blockIdx.y, bh = blockIdx.z;
  const int wm = (w >> 1) * 32, wn = (w & 1) * 32;
  f32x4 acc[2][2] = {};
#pragma unroll
  for (int i = 0; i < 2; ++i) {
    int e16 = i * 256 + tid;
    int row = e16 >> 3;
    int kb = (e16 & 7) * 16;
    int dst = row * 128 + (kb ^ ((row & 7) << 4));
    u32x4 vq = *(const u32x4*)((const char*)qbf + ((size_t)bh * 512 + lt * 64 + row) * 128 + kb);
    *(u32x4*)((char*)lQ + dst) = vq;
    u32x4 vk = *(const u32x4*)((const char*)kbf + ((size_t)bh * 512 + mt * 64 + row) * 128 + kb);
    *(u32x4*)((char*)lK + dst) = vk;
  }
  __syncthreads();
#pragma unroll
  for (int ks = 0; ks < 2; ++ks) {
    bf16x8 fa[2], fb[2];
    const int kbyte = (ks * 32 + (lane >> 4) * 8) * 2;
#pragma unroll
    for (int mi = 0; mi < 2; ++mi) {
      int row = wm + mi * 16 + (lane & 15);
      fa[mi] = *(const bf16x8*)((const char*)lQ + row * 128 + (kbyte ^ ((row & 7) << 4)));
    }
#pragma unroll
    for (int ni = 0; ni < 2; ++ni) {
      int row = wn + ni * 16 + (lane & 15);
      fb[ni] = *(const bf16x8*)((const char*)lK + row * 128 + (kbyte ^ ((row & 7) << 4)));
    }
#pragma unroll
    for (int mi = 0; mi < 2; ++mi)
#pragma unroll
      for (int ni = 0; ni < 2; ++ni)
        acc[mi][ni] = __builtin_amdgcn_mfma_f32_16x16x32_bf16(fa[mi], fb[ni], acc[mi][ni], 0, 0, 0);
  }
#pragma unroll
  for (int mi = 0; mi < 2; ++mi)
#pragma unroll
    for (int ni = 0; ni < 2; ++ni) {
      int gm = mt * 64 + wn + ni * 16 + (lane & 15);
#pragma unroll
      for (int r = 0; r < 4; ++r) {
        int gl = lt * 64 + wm + mi * 16 + ((lane >> 4) << 2) + r;
        Sb[(size_t)bh * 262144 + (size_t)gl * 512 + gm] = f2bf(acc[mi][ni][r]);
      }
    }
}

// ---------------- K2b: rel-K scores + softmax -> pbf, one block per (b,l) --
__global__ __launch_bounds__(256, 4) void k_relA(
    const unsigned short* __restrict__ qbf,
    const float* __restrict__ relk,   // [B][L][L][D]  (b, l, r, d)
    const unsigned short* __restrict__ Sb,
    unsigned short* __restrict__ pbf) {
  __shared__ __align__(16) char X[24576];   // S_rel [12][512] f32 swizzled
  const int tid = threadIdx.x, lane = tid & 63, w = tid >> 6;
  const int bl = blockIdx.x, b = bl >> 9, l = bl & 511;
  const int lm = lane & 15, lg = lane >> 4;
  const int hq = lm < 12 ? lm : 11;

  union { f32x4 f; bf16x8 b; } qa0, qa1;
  const char* aQ = (const char*)qbf + (((size_t)b * 12 + hq) * 512 + l) * 128 + (size_t)lg * 16;
  GL16(qa0.f, aQ, 0);
  GL16(qa1.f, aQ, 64);

  const char* aA = (const char*)relk + (size_t)bl * 131072 +
                   (size_t)(w * 128 + lm) * 256 + (size_t)lg * 32;
  f32x4 td[3][4];
#define TISSUE(t, s)                                                          \
  do {                                                                        \
    const char* p_ = aA + (size_t)(t) * 4096;                                 \
    GL16(td[s][0], p_, 0);   GL16(td[s][1], p_, 16);                          \
    GL16(td[s][2], p_, 128); GL16(td[s][3], p_, 144);                         \
  } while (0)
#define ACONSUME(t, s)                                                        \
  do {                                                                        \
    union { bf16x8 v; unsigned u[4]; } fb0, fb1;                              \
    fb0.u[0] = cvtpk(td[s][0][0], td[s][0][1]);                               \
    fb0.u[1] = cvtpk(td[s][0][2], td[s][0][3]);                               \
    fb0.u[2] = cvtpk(td[s][1][0], td[s][1][1]);                               \
    fb0.u[3] = cvtpk(td[s][1][2], td[s][1][3]);                               \
    fb1.u[0] = cvtpk(td[s][2][0], td[s][2][1]);                               \
    fb1.u[1] = cvtpk(td[s][2][2], td[s][2][3]);                               \
    fb1.u[2] = cvtpk(td[s][3][0], td[s][3][1]);                               \
    fb1.u[3] = cvtpk(td[s][3][2], td[s][3][3]);                               \
    f32x4 acc = {0.f, 0.f, 0.f, 0.f};                                         \
    acc = __builtin_amdgcn_mfma_f32_16x16x32_bf16(qa0.b, fb0.v, acc, 0, 0, 0);\
    acc = __builtin_amdgcn_mfma_f32_16x16x32_bf16(qa1.b, fb1.v, acc, 0, 0, 0);\
    if (lg < 3) {                                                             \
      const int r_ = w * 128 + (t) * 16 + lm;                                 \
      _Pragma("unroll")                                                       \
      for (int reg = 0; reg < 4; ++reg)                                       \
        *(float*)(X + (lg * 4 + reg) * 2048 + ((r_ * 4) ^ (lg << 6))) =       \
            acc[reg];                                                         \
    }                                                                         \
  } while (0)

  // Sb content prefetch (issued behind tiles 5..7; 24 loads in the queue)
  unsigned sreg[3][8];
  const char* aSb = (const char*)Sb +
      (((((size_t)b * 12 + w * 3) * 512 + l) * 512) + lane) * 2;
#define SRLOAD(hh)                                                            \
  do {                                                                        \
    const char* p_ = aSb + (size_t)(hh) * 524288;                             \
    GLU(sreg[hh][0], p_, 0);   GLU(sreg[hh][1], p_, 128);                     \
    GLU(sreg[hh][2], p_, 256); GLU(sreg[hh][3], p_, 384);                     \
    GLU(sreg[hh][4], p_, 512); GLU(sreg[hh][5], p_, 640);                     \
    GLU(sreg[hh][6], p_, 768); GLU(sreg[hh][7], p_, 896);                     \
  } while (0)

  TISSUE(0, 0); TISSUE(1, 1); TISSUE(2, 2);
  WAITV(8); ACONSUME(0, 0); TISSUE(3, 0);
  WAITV(8); ACONSUME(1, 1); TISSUE(4, 1);
  WAITV(8); ACONSUME(2, 2); TISSUE(5, 2);
  WAITV(8); ACONSUME(3, 0); TISSUE(6, 0);
  WAITV(8); ACONSUME(4, 1); TISSUE(7, 1);
  SRLOAD(0); SRLOAD(1); SRLOAD(2);       // queue: t5,t6,t7 (12) + 24 sreg
  WAITV(32); ACONSUME(5, 2);
  WAITV(28); ACONSUME(6, 0);
  WAITV(24); ACONSUME(7, 1);
#undef TISSUE
#undef ACONSUME
#undef SRLOAD

  lds_barrier();   // S_rel visible
  WAITV(0);        // sreg landed (latency hidden under consumes + barrier)

  // softmax; wave owns h = 3w..3w+2
#pragma unroll
  for (int hh = 0; hh < 3; ++hh) {
    const int h = w * 3 + hh;
    const int sw = ((h >> 2) & 3) << 6;
    const size_t srow = (((size_t)b * 12 + h) * 512 + l) * 512;
    float sv[8];
    float mx = -1e30f;
#pragma unroll
    for (int j = 0; j < 8; ++j) {
      const int r = j * 64 + lane;
      float s = (*(const float*)(X + h * 2048 + ((r * 4) ^ sw)) + ubf(sreg[hh][j])) * 0.125f;
      sv[j] = s;
      mx = fmaxf(mx, s);
    }
#pragma unroll
    for (int off = 32; off; off >>= 1) mx = fmaxf(mx, __shfl_xor(mx, off));
    float sm = 0.f;
#pragma unroll
    for (int j = 0; j < 8; ++j) { sv[j] = __expf(sv[j] - mx); sm += sv[j]; }
#pragma unroll
    for (int off = 32; off; off >>= 1) sm += __shfl_xor(sm, off);
    const float inv = 1.f / sm;
#pragma unroll
    for (int j = 0; j < 8; ++j)
      pbf[srow + j * 64 + lane] = f2bf(sv[j] * inv);
  }
}

// ---------------- K2c: rel-V context, contiguous streaming ----------------
// block = (lg, rc8, b): r in [rc*64, +64), l in [lg*16, +16)
// wave owns 4 l's; lane: l = l0 + w*4 + (lane>>4), d-quad = (lane&15)*4
__global__ __launch_bounds__(256, 3) void k_relv(
    const unsigned short* __restrict__ pbf,   // [B][H][L][R] bf16
    const float* __restrict__ relv,           // [B][R][L][D] f32
    unsigned short* __restrict__ part) {      // [8 rc][B][L][768] bf16
  __shared__ __align__(16) char PS[24576];    // P [12][16][64] bf16 swizzled
  const int tid = threadIdx.x, lane = tid & 63, w = tid >> 6;
  const int lg = blockIdx.x, rc = blockIdx.y, b = blockIdx.z;
  const int l0 = lg * 16, r0 = rc * 64;

  // stage P slice: rows (h, lr) of 64 bf16 (128B); 6 passes x 32 rows
  {
    const int x = tid & 7, rowb = tid >> 3;
#pragma unroll
    for (int pass = 0; pass < 6; ++pass) {
      const int ri = pass * 32 + rowb;        // 0..191
      const int h = ri >> 4, lr = ri & 15;
      const char* src = (const char*)pbf +
          ((((size_t)b * 12 + h) * 512 + l0 + lr) * 512 + r0) * 2 + (size_t)x * 16;
      u32x4 v = *(const u32x4*)src;
      *(u32x4*)(PS + h * 2048 + lr * 128 + ((x * 16) ^ ((lr & 3) << 4))) = v;
    }
  }
  __syncthreads();

  const int lr_w = w * 4 + (lane >> 4);       // local l, 0..15
  const int l = l0 + lr_w;
  const char* rvb = (const char*)relv +
      (((size_t)b * 512 + r0) * 512 + l) * 256 + (size_t)(lane & 15) * 16;

  f32x4 vA[8], vB[8];
  f32x4 acc[12];
#pragma unroll
  for (int h = 0; h < 12; ++h) acc[h] = {0.f, 0.f, 0.f, 0.f};

#define VISSUE(o, buf)                                                        \
  do {                                                                        \
    GL16(buf[0], rvb + (size_t)((o) * 8 + 0) * 131072, 0);                    \
    GL16(buf[1], rvb + (size_t)((o) * 8 + 1) * 131072, 0);                    \
    GL16(buf[2], rvb + (size_t)((o) * 8 + 2) * 131072, 0);                    \
    GL16(buf[3], rvb + (size_t)((o) * 8 + 3) * 131072, 0);                    \
    GL16(buf[4], rvb + (size_t)((o) * 8 + 4) * 131072, 0);                    \
    GL16(buf[5], rvb + (size_t)((o) * 8 + 5) * 131072, 0);                    \
    GL16(buf[6], rvb + (size_t)((o) * 8 + 6) * 131072, 0);                    \
    GL16(buf[7], rvb + (size_t)((o) * 8 + 7) * 131072, 0);                    \
  } while (0)
#define VCONS(o, buf)                                                         \
  do {                                                                        \
    _Pragma("unroll")                                                         \
    for (int h = 0; h < 12; ++h) {                                            \
      bf16x8 p8 = *(const bf16x8*)(PS + h * 2048 + lr_w * 128 +               \
                                   (((o) * 16) ^ ((lr_w & 3) << 4)));         \
      _Pragma("unroll")                                                       \
      for (int j = 0; j < 8; ++j) {                                           \
        const float pf = bf2f((unsigned short)p8[j]);                         \
        acc[h] += pf * buf[j];                                                \
      }                                                                       \
    }                                                                         \
  } while (0)

  VISSUE(0, vA);
  VISSUE(1, vB);
  WAITV(8); VCONS(0, vA); VISSUE(2, vA);
  WAITV(8); VCONS(1, vB); VISSUE(3, vB);
  WAITV(8); VCONS(2, vA); VISSUE(4, vA);
  WAITV(8); VCONS(3, vB); VISSUE(5, vB);
  WAITV(8); VCONS(4, vA); VISSUE(6, vA);
  WAITV(8); VCONS(5, vB); VISSUE(7, vB);
  WAITV(8); VCONS(6, vA);
  WAITV(0); VCONS(7, vB);
#undef VISSUE
#undef VCONS

  // write partial bf16: [rc][b][l][h*64 + dq*4 .. +3]
  unsigned short* op = part + ((size_t)rc * 2048 + (size_t)b * 512 + l) * 768 + (lane & 15) * 4;
#pragma unroll
  for (int h = 0; h < 12; ++h) {
    u32x2 pk;
    pk.x = cvtpk(acc[h][0], acc[h][1]);
    pk.y = cvtpk(acc[h][2], acc[h][3]);
    *(u32x2*)(op + h * 64) = pk;
  }
}

// ---------------- K3: ctx = P@V per (b,h) via MFMA, + 8 bf16 partials -----
__global__ __launch_bounds__(256) void k_pv(
    const unsigned short* __restrict__ pbf, const unsigned short* __restrict__ vbt,
    const unsigned short* __restrict__ part, float* __restrict__ out) {
  __shared__ __align__(16) unsigned short lP[64 * 64];
  __shared__ __align__(16) unsigned short lV[64 * 64];
  const int tid = threadIdx.x, lane = tid & 63, w = tid >> 6;
  const int lt = blockIdx.x, bh = blockIdx.y;
  const int b = bh / 12, h = bh % 12;
  const int wm = (w >> 1) * 32, wn = (w & 1) * 32;
  f32x4 acc[2][2] = {};
  const char* pbase = (const char*)pbf + ((size_t)bh * 512 + lt * 64) * 1024;
  const char* vbase = (const char*)vbt + (size_t)bh * 64 * 1024;
  for (int kt = 0; kt < 8; ++kt) {
    __syncthreads();
#pragma unroll
    for (int i = 0; i < 2; ++i) {
      int e16 = i * 256 + tid;
      int row = e16 >> 3;
      int kb = (e16 & 7) * 16;
      int dst = row * 128 + (kb ^ ((row & 7) << 4));
      u32x4 vp = *(const u32x4*)(pbase + (size_t)row * 1024 + kt * 128 + kb);
      *(u32x4*)((char*)lP + dst) = vp;
      u32x4 vv = *(const u32x4*)(vbase + (size_t)row * 1024 + kt * 128 + kb);
      *(u32x4*)((char*)lV + dst) = vv;
    }
    __syncthreads();
#pragma unroll
    for (int ks = 0; ks < 2; ++ks) {
      bf16x8 fa[2], fb[2];
      const int kbyte = (ks * 32 + (lane >> 4) * 8) * 2;
#pragma unroll
      for (int mi = 0; mi < 2; ++mi) {
        int row = wm + mi * 16 + (lane & 15);
        fa[mi] = *(const bf16x8*)((const char*)lP + row * 128 + (kbyte ^ ((row & 7) << 4)));
      }
#pragma unroll
      for (int ni = 0; ni < 2; ++ni) {
        int row = wn + ni * 16 + (lane & 15);
        fb[ni] = *(const bf16x8*)((const char*)lV + row * 128 + (kbyte ^ ((row & 7) << 4)));
      }
#pragma unroll
      for (int mi = 0; mi < 2; ++mi)
#pragma unroll
        for (int ni = 0; ni < 2; ++ni)
          acc[mi][ni] = __builtin_amdgcn_mfma_f32_16x16x32_bf16(fa[mi], fb[ni], acc[mi][ni], 0, 0, 0);
    }
  }
#pragma unroll
  for (int mi = 0; mi < 2; ++mi)
#pragma unroll
    for (int ni = 0; ni < 2; ++ni) {
      int gd = wn + ni * 16 + (lane & 15);
#pragma unroll
      for (int r = 0; r < 4; ++r) {
        int gl = lt * 64 + wm + mi * 16 + ((lane >> 4) << 2) + r;
        size_t o = ((size_t)b * 512 + gl) * 768 + h * 64 + gd;
        float s = acc[mi][ni][r];
#pragma unroll
        for (int k = 0; k < 8; ++k) s += bf2f(part[o + (size_t)k * 1572864]);
        out[o] = s;
      }
    }
}

extern "C" void kernel_launch(void* const* d_in, const int* in_sizes, int n_in,
                              void* d_out, int out_size, void* d_ws, size_t ws_size,
                              hipStream_t stream) {
  (void)in_sizes; (void)n_in; (void)out_size; (void)ws_size;
  const float* hidden = (const float*)d_in[0];
  const float* relk   = (const float*)d_in[1];
  const float* relv   = (const float*)d_in[2];
  const float* Wq     = (const float*)d_in[3];
  const float* bq     = (const float*)d_in[4];
  const float* Wk     = (const float*)d_in[5];
  const float* bk     = (const float*)d_in[6];
  const float* Wv     = (const float*)d_in[7];
  const float* bv     = (const float*)d_in[8];
  float* out = (float*)d_out;
  char* ws = (char*)d_ws;

  unsigned short* hb  = (unsigned short*)(ws);
  unsigned short* wt  = (unsigned short*)(ws + 3145728);
  unsigned short* qbf = (unsigned short*)(ws + 6684672);
  unsigned short* kbf = (unsigned short*)(ws + 9830400);
  unsigned short* vbt = (unsigned short*)(ws + 12976128);
  unsigned short* Sb  = (unsigned short*)(ws + 16121856);  // 25.2 MB, dead after k_relA
  unsigned short* part= (unsigned short*)(ws + 16121856);  // 25.2 MB overlay (post-k_relA)
  unsigned short* pbf = (unsigned short*)(ws + 66453504);

  k_cvt_hidden<<<1536, 256, 0, stream>>>(hidden, hb);
  k_transp_w<<<dim3(12, 12, 3), 256, 0, stream>>>(Wq, Wk, Wv, wt);
  k_qkv_gemm<<<dim3(32, 36), 256, 0, stream>>>(hb, wt, bq, bk, bv, qbf, kbf, vbt);
  k_scores<<<dim3(8, 8, 48), 256, 0, stream>>>(qbf, kbf, Sb);
  k_relA<<<2048, 256, 0, stream>>>(qbf, relk, Sb, pbf);
  k_relv<<<dim3(32, 8, 4), 256, 0, stream>>>(pbf, relv, part);
  k_pv<<<dim3(8, 48), 256, 0, stream>>>(pbf, vbt, part, out);
}

// Round 10
// 180.962 us; speedup vs baseline: 1.0540x; 1.0540x over previous
//
#include <hip/hip_runtime.h>
#include <stdint.h>

// BertSelfAttentionWithRelation  B=4 L=512 H=12 D=64 HIDDEN=768
// Round 10: R8 base (best, 186.4us) + occupancy/launch fixes.
//   k_prep: merged hidden-cvt + W-transpose (one launch)
//   k_relA: S_rel LDS buffer bf16 (12.3KB, swz <<5), bounds(256,5)
//   k_relv: R8 version (rc=4, 3-slot), k_pv: 4 bf16 partials

typedef __attribute__((ext_vector_type(8))) short bf16x8;
typedef __attribute__((ext_vector_type(4))) float f32x4;
typedef __attribute__((ext_vector_type(4))) unsigned int u32x4;
typedef __attribute__((ext_vector_type(2))) unsigned int u32x2;

__device__ __forceinline__ unsigned short f2bf(float f) {
  union { float f; unsigned int u; } v; v.f = f;
  unsigned int r = v.u + 0x7fffu + ((v.u >> 16) & 1u);
  return (unsigned short)(r >> 16);
}
__device__ __forceinline__ float bf2f(unsigned short s) {
  union { unsigned int u; float f; } v; v.u = ((unsigned int)s) << 16;
  return v.f;
}
__device__ __forceinline__ void lds_barrier() {
  asm volatile("s_waitcnt lgkmcnt(0)\ns_barrier" ::: "memory");
}
__device__ __forceinline__ unsigned cvtpk(float lo, float hi) {
  unsigned r;
  asm("v_cvt_pk_bf16_f32 %0, %1, %2" : "=v"(r) : "v"(lo), "v"(hi));
  return r;
}

#define GL16(dst, addr, OFF)                                                  \
  asm volatile("global_load_dwordx4 %0, %1, off offset:" #OFF                \
               : "=v"(dst) : "v"(addr))
#define WAITV(N)                                                              \
  do {                                                                        \
    asm volatile("s_waitcnt vmcnt(" #N ")" ::: "memory");                     \
    __builtin_amdgcn_sched_barrier(0);                                        \
  } while (0)

// ---------------- K0: merged hidden cvt + W transpose ----------------
// blocks 0..431: W transpose (wsel, kt, nt); blocks 432..1967: hidden cvt
__global__ void k_prep(const float* __restrict__ hidden,
                       const float* __restrict__ Wq, const float* __restrict__ Wk,
                       const float* __restrict__ Wv,
                       unsigned short* __restrict__ hb,
                       unsigned short* __restrict__ wt) {
  __shared__ float t[64][65];
  const int bid = blockIdx.x;
  if (bid >= 432) {
    int i = (bid - 432) * 256 + threadIdx.x;   // 1536*256 float4s exactly
    float4 v = reinterpret_cast<const float4*>(hidden)[i];
    ushort4 o;
    o.x = f2bf(v.x); o.y = f2bf(v.y); o.z = f2bf(v.z); o.w = f2bf(v.w);
    reinterpret_cast<ushort4*>(hb)[i] = o;
    return;
  }
  const int wsel = bid / 144, rem = bid % 144;
  const int kt = rem / 12, nt = rem % 12;
  const float* W = wsel == 0 ? Wq : (wsel == 1 ? Wk : Wv);
  const int lx = threadIdx.x & 63, ly = threadIdx.x >> 6;
  for (int i = 0; i < 64; i += 4)
    t[ly + i][lx] = W[(size_t)(kt * 64 + ly + i) * 768 + nt * 64 + lx];
  __syncthreads();
  for (int i = 0; i < 64; i += 4) {
    int r = ly + i;
    wt[((size_t)wsel * 768 + nt * 64 + r) * 768 + kt * 64 + lx] = f2bf(t[lx][r]);
  }
}

// ---------------- K1: fused QKV GEMM (bf16 MFMA) ----------------
__global__ __launch_bounds__(256) void k_qkv_gemm(
    const unsigned short* __restrict__ A, const unsigned short* __restrict__ Bt,
    const float* __restrict__ bq, const float* __restrict__ bk, const float* __restrict__ bv,
    unsigned short* __restrict__ qbf, unsigned short* __restrict__ kbf,
    unsigned short* __restrict__ vbt) {
  __shared__ __align__(16) unsigned short lA[64 * 64];
  __shared__ __align__(16) unsigned short lB[64 * 64];
  const int tid = threadIdx.x, lane = tid & 63, w = tid >> 6;
  const int m0 = blockIdx.x * 64, n0 = blockIdx.y * 64;
  const int wm = (w >> 1) * 32, wn = (w & 1) * 32;
  f32x4 acc[2][2] = {};

  for (int kt = 0; kt < 12; ++kt) {
    __syncthreads();
#pragma unroll
    for (int i = 0; i < 2; ++i) {
      int e16 = i * 256 + tid;
      int row = e16 >> 3;
      int kb = (e16 & 7) * 16;
      int dst = row * 128 + (kb ^ ((row & 7) << 4));
      u32x4 va = *(const u32x4*)((const char*)A + (size_t)(m0 + row) * 1536 + kt * 128 + kb);
      *(u32x4*)((char*)lA + dst) = va;
      u32x4 vb = *(const u32x4*)((const char*)Bt + (size_t)(n0 + row) * 1536 + kt * 128 + kb);
      *(u32x4*)((char*)lB + dst) = vb;
    }
    __syncthreads();
#pragma unroll
    for (int ks = 0; ks < 2; ++ks) {
      bf16x8 fa[2], fb[2];
      const int kbyte = (ks * 32 + (lane >> 4) * 8) * 2;
#pragma unroll
      for (int mi = 0; mi < 2; ++mi) {
        int row = wm + mi * 16 + (lane & 15);
        fa[mi] = *(const bf16x8*)((const char*)lA + row * 128 + (kbyte ^ ((row & 7) << 4)));
      }
#pragma unroll
      for (int ni = 0; ni < 2; ++ni) {
        int row = wn + ni * 16 + (lane & 15);
        fb[ni] = *(const bf16x8*)((const char*)lB + row * 128 + (kbyte ^ ((row & 7) << 4)));
      }
#pragma unroll
      for (int mi = 0; mi < 2; ++mi)
#pragma unroll
        for (int ni = 0; ni < 2; ++ni)
          acc[mi][ni] = __builtin_amdgcn_mfma_f32_16x16x32_bf16(fa[mi], fb[ni], acc[mi][ni], 0, 0, 0);
    }
  }
#pragma unroll
  for (int mi = 0; mi < 2; ++mi)
#pragma unroll
    for (int ni = 0; ni < 2; ++ni) {
      int gn = n0 + wn + ni * 16 + (lane & 15);
      float bias = (gn < 768) ? bq[gn] : (gn < 1536 ? bk[gn - 768] : bv[gn - 1536]);
#pragma unroll
      for (int r = 0; r < 4; ++r) {
        int gm = m0 + wm + mi * 16 + ((lane >> 4) << 2) + r;
        float val = acc[mi][ni][r] + bias;
        int b = gm >> 9, l = gm & 511;
        int d = gn & 63;
        if (gn < 768) {
          int h = gn >> 6;
          qbf[(((size_t)(b * 12 + h)) * 512 + l) * 64 + d] = f2bf(val);
        } else if (gn < 1536) {
          int h = (gn - 768) >> 6;
          kbf[(((size_t)(b * 12 + h)) * 512 + l) * 64 + d] = f2bf(val);
        } else {
          int h = (gn - 1536) >> 6;
          vbt[(((size_t)(b * 12 + h)) * 64 + d) * 512 + l] = f2bf(val);
        }
      }
    }
}

// ---------------- K2a: content scores S = q.k^T per (b,h), bf16 out -------
__global__ __launch_bounds__(256) void k_scores(
    const unsigned short* __restrict__ qbf, const unsigned short* __restrict__ kbf,
    unsigned short* __restrict__ Sb) {
  __shared__ __align__(16) unsigned short lQ[64 * 64];
  __shared__ __align__(16) unsigned short lK[64 * 64];
  const int tid = threadIdx.x, lane = tid & 63, w = tid >> 6;
  const int mt = blockIdx.x, lt = blockIdx.y, bh = blockIdx.z;
  const int wm = (w >> 1) * 32, wn = (w & 1) * 32;
  f32x4 acc[2][2] = {};
#pragma unroll
  for (int i = 0; i < 2; ++i) {
    int e16 = i * 256 + tid;
    int row = e16 >> 3;
    int kb = (e16 & 7) * 16;
    int dst = row * 128 + (kb ^ ((row & 7) << 4));
    u32x4 vq = *(const u32x4*)((const char*)qbf + ((size_t)bh * 512 + lt * 64 + row) * 128 + kb);
    *(u32x4*)((char*)lQ + dst) = vq;
    u32x4 vk = *(const u32x4*)((const char*)kbf + ((size_t)bh * 512 + mt * 64 + row) * 128 + kb);
    *(u32x4*)((char*)lK + dst) = vk;
  }
  __syncthreads();
#pragma unroll
  for (int ks = 0; ks < 2; ++ks) {
    bf16x8 fa[2], fb[2];
    const int kbyte = (ks * 32 + (lane >> 4) * 8) * 2;
#pragma unroll
    for (int mi = 0; mi < 2; ++mi) {
      int row = wm + mi * 16 + (lane & 15);
      fa[mi] = *(const bf16x8*)((const char*)lQ + row * 128 + (kbyte ^ ((row & 7) << 4)));
    }
#pragma unroll
    for (int ni = 0; ni < 2; ++ni) {
      int row = wn + ni * 16 + (lane & 15);
      fb[ni] = *(const bf16x8*)((const char*)lK + row * 128 + (kbyte ^ ((row & 7) << 4)));
    }
#pragma unroll
    for (int mi = 0; mi < 2; ++mi)
#pragma unroll
      for (int ni = 0; ni < 2; ++ni)
        acc[mi][ni] = __builtin_amdgcn_mfma_f32_16x16x32_bf16(fa[mi], fb[ni], acc[mi][ni], 0, 0, 0);
  }
#pragma unroll
  for (int mi = 0; mi < 2; ++mi)
#pragma unroll
    for (int ni = 0; ni < 2; ++ni) {
      int gm = mt * 64 + wn + ni * 16 + (lane & 15);
#pragma unroll
      for (int r = 0; r < 4; ++r) {
        int gl = lt * 64 + wm + mi * 16 + ((lane >> 4) << 2) + r;
        Sb[(size_t)bh * 262144 + (size_t)gl * 512 + gm] = f2bf(acc[mi][ni][r]);
      }
    }
}

// ---------------- K2b: rel-K scores + softmax -> pbf, one block per (b,l) --
// X is S_rel [12][512] bf16 (12.3 KB), swizzle ((h>>2)&3)<<5 so the three
// active lane-groups (h quads) hit disjoint bank groups on writes.
__global__ __launch_bounds__(256, 5) void k_relA(
    const unsigned short* __restrict__ qbf,
    const float* __restrict__ relk,   // [B][L][L][D]  (b, l, r, d)
    const unsigned short* __restrict__ Sb,
    unsigned short* __restrict__ pbf) {
  __shared__ __align__(16) char X[12288];
  const int tid = threadIdx.x, lane = tid & 63, w = tid >> 6;
  const int bl = blockIdx.x, b = bl >> 9, l = bl & 511;
  const int lm = lane & 15, lg = lane >> 4;
  const int hq = lm < 12 ? lm : 11;

  union { f32x4 f; bf16x8 b; } qa0, qa1;
  const char* aQ = (const char*)qbf + (((size_t)b * 12 + hq) * 512 + l) * 128 + (size_t)lg * 16;
  GL16(qa0.f, aQ, 0);
  GL16(qa1.f, aQ, 64);

  const char* aA = (const char*)relk + (size_t)bl * 131072 +
                   (size_t)(w * 128 + lm) * 256 + (size_t)lg * 32;
  f32x4 td[3][4];
#define TISSUE(t, s)                                                          \
  do {                                                                        \
    const char* p_ = aA + (size_t)(t) * 4096;                                 \
    GL16(td[s][0], p_, 0);   GL16(td[s][1], p_, 16);                          \
    GL16(td[s][2], p_, 128); GL16(td[s][3], p_, 144);                         \
  } while (0)
#define ACONSUME(t, s)                                                        \
  do {                                                                        \
    union { bf16x8 v; unsigned u[4]; } fb0, fb1;                              \
    fb0.u[0] = cvtpk(td[s][0][0], td[s][0][1]);                               \
    fb0.u[1] = cvtpk(td[s][0][2], td[s][0][3]);                               \
    fb0.u[2] = cvtpk(td[s][1][0], td[s][1][1]);                               \
    fb0.u[3] = cvtpk(td[s][1][2], td[s][1][3]);                               \
    fb1.u[0] = cvtpk(td[s][2][0], td[s][2][1]);                               \
    fb1.u[1] = cvtpk(td[s][2][2], td[s][2][3]);                               \
    fb1.u[2] = cvtpk(td[s][3][0], td[s][3][1]);                               \
    fb1.u[3] = cvtpk(td[s][3][2], td[s][3][3]);                               \
    f32x4 acc = {0.f, 0.f, 0.f, 0.f};                                         \
    acc = __builtin_amdgcn_mfma_f32_16x16x32_bf16(qa0.b, fb0.v, acc, 0, 0, 0);\
    acc = __builtin_amdgcn_mfma_f32_16x16x32_bf16(qa1.b, fb1.v, acc, 0, 0, 0);\
    if (lg < 3) {                                                             \
      const int r_ = w * 128 + (t) * 16 + lm;                                 \
      _Pragma("unroll")                                                       \
      for (int reg = 0; reg < 4; ++reg) {                                     \
        const int h_ = lg * 4 + reg;                                          \
        *(unsigned short*)(X + h_ * 1024 +                                    \
                           ((r_ * 2) ^ (((h_ >> 2) & 3) << 5))) =             \
            f2bf(acc[reg]);                                                   \
      }                                                                       \
    }                                                                         \
  } while (0)

  TISSUE(0, 0); TISSUE(1, 1); TISSUE(2, 2);
  WAITV(8); ACONSUME(0, 0); TISSUE(3, 0);
  WAITV(8); ACONSUME(1, 1); TISSUE(4, 1);
  WAITV(8); ACONSUME(2, 2); TISSUE(5, 2);
  WAITV(8); ACONSUME(3, 0); TISSUE(6, 0);
  WAITV(8); ACONSUME(4, 1); TISSUE(7, 1);
  WAITV(8); ACONSUME(5, 2);
  WAITV(4); ACONSUME(6, 0);
  WAITV(0); ACONSUME(7, 1);
#undef TISSUE
#undef ACONSUME

  lds_barrier();   // S_rel visible

  // softmax; wave owns h = 3w..3w+2; content Sb (bf16) loaded inline
#pragma unroll
  for (int hh = 0; hh < 3; ++hh) {
    const int h = w * 3 + hh;
    const int sw = ((h >> 2) & 3) << 5;
    const size_t srow = (((size_t)b * 12 + h) * 512 + l) * 512;
    const unsigned short* sp = Sb + srow + lane;
    float sv[8];
    float mx = -1e30f;
#pragma unroll
    for (int j = 0; j < 8; ++j) {
      const int r = j * 64 + lane;
      float sr = bf2f(*(const unsigned short*)(X + h * 1024 + ((r * 2) ^ sw)));
      float s = (sr + bf2f(sp[j * 64])) * 0.125f;
      sv[j] = s;
      mx = fmaxf(mx, s);
    }
#pragma unroll
    for (int off = 32; off; off >>= 1) mx = fmaxf(mx, __shfl_xor(mx, off));
    float sm = 0.f;
#pragma unroll
    for (int j = 0; j < 8; ++j) { sv[j] = __expf(sv[j] - mx); sm += sv[j]; }
#pragma unroll
    for (int off = 32; off; off >>= 1) sm += __shfl_xor(sm, off);
    const float inv = 1.f / sm;
#pragma unroll
    for (int j = 0; j < 8; ++j)
      pbf[srow + j * 64 + lane] = f2bf(sv[j] * inv);
  }
}

// ---------------- K2c: rel-V context, contiguous streaming (R8) -----------
__global__ __launch_bounds__(256, 2) void k_relv(
    const unsigned short* __restrict__ pbf,   // [B][H][L][R] bf16
    const float* __restrict__ relv,           // [B][R][L][D] f32
    unsigned short* __restrict__ part) {      // [4 rc][B][L][768] bf16
  __shared__ __align__(16) char PS[49152];    // P [12][16][128] bf16 swizzled
  const int tid = threadIdx.x, lane = tid & 63, w = tid >> 6;
  const int lg = blockIdx.x, rc = blockIdx.y, b = blockIdx.z;
  const int l0 = lg * 16, r0 = rc * 128;

  {
    const int x = tid & 15, rowb = tid >> 4;
#pragma unroll
    for (int pass = 0; pass < 12; ++pass) {
      const int ri = pass * 16 + rowb;
      const int h = ri >> 4, lr = ri & 15;
      const char* src = (const char*)pbf +
          ((((size_t)b * 12 + h) * 512 + l0 + lr) * 512 + r0) * 2 + (size_t)x * 16;
      u32x4 v = *(const u32x4*)src;
      *(u32x4*)(PS + h * 4096 + lr * 256 + ((x * 16) ^ ((lr & 3) << 4))) = v;
    }
  }
  __syncthreads();

  const int lr_w = w * 4 + (lane >> 4);
  const int l = l0 + lr_w;
  const char* rvb = (const char*)relv +
      (((size_t)b * 512 + r0) * 512 + l) * 256 + (size_t)(lane & 15) * 16;

  f32x4 vA[8], vB[8], vC[8];
  f32x4 acc[12];
#pragma unroll
  for (int h = 0; h < 12; ++h) acc[h] = {0.f, 0.f, 0.f, 0.f};

#define VISSUE(o, buf)                                                        \
  do {                                                                        \
    GL16(buf[0], rvb + (size_t)((o) * 8 + 0) * 131072, 0);                    \
    GL16(buf[1], rvb + (size_t)((o) * 8 + 1) * 131072, 0);                    \
    GL16(buf[2], rvb + (size_t)((o) * 8 + 2) * 131072, 0);                    \
    GL16(buf[3], rvb + (size_t)((o) * 8 + 3) * 131072, 0);                    \
    GL16(buf[4], rvb + (size_t)((o) * 8 + 4) * 131072, 0);                    \
    GL16(buf[5], rvb + (size_t)((o) * 8 + 5) * 131072, 0);                    \
    GL16(buf[6], rvb + (size_t)((o) * 8 + 6) * 131072, 0);                    \
    GL16(buf[7], rvb + (size_t)((o) * 8 + 7) * 131072, 0);                    \
  } while (0)
#define VCONS(o, buf)                                                         \
  do {                                                                        \
    _Pragma("unroll")                                                         \
    for (int h = 0; h < 12; ++h) {                                            \
      bf16x8 p8 = *(const bf16x8*)(PS + h * 4096 + lr_w * 256 +               \
                                   (((o) * 16) ^ ((lr_w & 3) << 4)));         \
      _Pragma("unroll")                                                       \
      for (int j = 0; j < 8; ++j) {                                           \
        const float pf = bf2f((unsigned short)p8[j]);                         \
        acc[h] += pf * buf[j];                                                \
      }                                                                       \
    }                                                                         \
  } while (0)

  VISSUE(0, vA);
  VISSUE(1, vB);
  VISSUE(2, vC);
  WAITV(16); VCONS(0, vA);  VISSUE(3, vA);
  WAITV(16); VCONS(1, vB);  VISSUE(4, vB);
  WAITV(16); VCONS(2, vC);  VISSUE(5, vC);
  WAITV(16); VCONS(3, vA);  VISSUE(6, vA);
  WAITV(16); VCONS(4, vB);  VISSUE(7, vB);
  WAITV(16); VCONS(5, vC);  VISSUE(8, vC);
  WAITV(16); VCONS(6, vA);  VISSUE(9, vA);
  WAITV(16); VCONS(7, vB);  VISSUE(10, vB);
  WAITV(16); VCONS(8, vC);  VISSUE(11, vC);
  WAITV(16); VCONS(9, vA);  VISSUE(12, vA);
  WAITV(16); VCONS(10, vB); VISSUE(13, vB);
  WAITV(16); VCONS(11, vC); VISSUE(14, vC);
  WAITV(16); VCONS(12, vA); VISSUE(15, vA);
  WAITV(16); VCONS(13, vB);
  WAITV(8);  VCONS(14, vC);
  WAITV(0);  VCONS(15, vA);
#undef VISSUE
#undef VCONS

  unsigned short* op = part + ((size_t)rc * 2048 + (size_t)b * 512 + l) * 768 + (lane & 15) * 4;
#pragma unroll
  for (int h = 0; h < 12; ++h) {
    u32x2 pk;
    pk.x = cvtpk(acc[h][0], acc[h][1]);
    pk.y = cvtpk(acc[h][2], acc[h][3]);
    *(u32x2*)(op + h * 64) = pk;
  }
}

// ---------------- K3: ctx = P@V per (b,h) via MFMA, + 4 bf16 partials -----
__global__ __launch_bounds__(256) void k_pv(
    const unsigned short* __restrict__ pbf, const unsigned short* __restrict__ vbt,
    const unsigned short* __restrict__ part, float* __restrict__ out) {
  __shared__ __align__(16) unsigned short lP[64 * 64];
  __shared__ __align__(16) unsigned short lV[64 * 64];
  const int tid = threadIdx.x, lane = tid & 63, w = tid >> 6;
  const int lt = blockIdx.x, bh = blockIdx.y;
  const int b = bh / 12, h = bh % 12;
  const int wm = (w >> 1) * 32, wn = (w & 1) * 32;
  f32x4 acc[2][2] = {};
  const char* pbase = (const char*)pbf + ((size_t)bh * 512 + lt * 64) * 1024;
  const char* vbase = (const char*)vbt + (size_t)bh * 64 * 1024;
  for (int kt = 0; kt < 8; ++kt) {
    __syncthreads();
#pragma unroll
    for (int i = 0; i < 2; ++i) {
      int e16 = i * 256 + tid;
      int row = e16 >> 3;
      int kb = (e16 & 7) * 16;
      int dst = row * 128 + (kb ^ ((row & 7) << 4));
      u32x4 vp = *(const u32x4*)(pbase + (size_t)row * 1024 + kt * 128 + kb);
      *(u32x4*)((char*)lP + dst) = vp;
      u32x4 vv = *(const u32x4*)(vbase + (size_t)row * 1024 + kt * 128 + kb);
      *(u32x4*)((char*)lV + dst) = vv;
    }
    __syncthreads();
#pragma unroll
    for (int ks = 0; ks < 2; ++ks) {
      bf16x8 fa[2], fb[2];
      const int kbyte = (ks * 32 + (lane >> 4) * 8) * 2;
#pragma unroll
      for (int mi = 0; mi < 2; ++mi) {
        int row = wm + mi * 16 + (lane & 15);
        fa[mi] = *(const bf16x8*)((const char*)lP + row * 128 + (kbyte ^ ((row & 7) << 4)));
      }
#pragma unroll
      for (int ni = 0; ni < 2; ++ni) {
        int row = wn + ni * 16 + (lane & 15);
        fb[ni] = *(const bf16x8*)((const char*)lV + row * 128 + (kbyte ^ ((row & 7) << 4)));
      }
#pragma unroll
      for (int mi = 0; mi < 2; ++mi)
#pragma unroll
        for (int ni = 0; ni < 2; ++ni)
          acc[mi][ni] = __builtin_amdgcn_mfma_f32_16x16x32_bf16(fa[mi], fb[ni], acc[mi][ni], 0, 0, 0);
    }
  }
#pragma unroll
  for (int mi = 0; mi < 2; ++mi)
#pragma unroll
    for (int ni = 0; ni < 2; ++ni) {
      int gd = wn + ni * 16 + (lane & 15);
#pragma unroll
      for (int r = 0; r < 4; ++r) {
        int gl = lt * 64 + wm + mi * 16 + ((lane >> 4) << 2) + r;
        size_t o = ((size_t)b * 512 + gl) * 768 + h * 64 + gd;
        out[o] = acc[mi][ni][r] + bf2f(part[o]) + bf2f(part[o + 1572864]) +
                 bf2f(part[o + 3145728]) + bf2f(part[o + 4718592]);
      }
    }
}

extern "C" void kernel_launch(void* const* d_in, const int* in_sizes, int n_in,
                              void* d_out, int out_size, void* d_ws, size_t ws_size,
                              hipStream_t stream) {
  (void)in_sizes; (void)n_in; (void)out_size; (void)ws_size;
  const float* hidden = (const float*)d_in[0];
  const float* relk   = (const float*)d_in[1];
  const float* relv   = (const float*)d_in[2];
  const float* Wq     = (const float*)d_in[3];
  const float* bq     = (const float*)d_in[4];
  const float* Wk     = (const float*)d_in[5];
  const float* bk     = (const float*)d_in[6];
  const float* Wv     = (const float*)d_in[7];
  const float* bv     = (const float*)d_in[8];
  float* out = (float*)d_out;
  char* ws = (char*)d_ws;

  unsigned short* hb  = (unsigned short*)(ws);
  unsigned short* wt  = (unsigned short*)(ws + 3145728);
  unsigned short* qbf = (unsigned short*)(ws + 6684672);
  unsigned short* kbf = (unsigned short*)(ws + 9830400);
  unsigned short* vbt = (unsigned short*)(ws + 12976128);
  unsigned short* Sb  = (unsigned short*)(ws + 16121856);  // dead after k_relA
  unsigned short* part= (unsigned short*)(ws + 16121856);  // 12.6 MB overlay
  unsigned short* pbf = (unsigned short*)(ws + 66453504);

  k_prep<<<1968, 256, 0, stream>>>(hidden, Wq, Wk, Wv, hb, wt);
  k_qkv_gemm<<<dim3(32, 36), 256, 0, stream>>>(hb, wt, bq, bk, bv, qbf, kbf, vbt);
  k_scores<<<dim3(8, 8, 48), 256, 0, stream>>>(qbf, kbf, Sb);
  k_relA<<<2048, 256, 0, stream>>>(qbf, relk, Sb, pbf);
  k_relv<<<dim3(32, 4, 4), 256, 0, stream>>>(pbf, relv, part);
  k_pv<<<dim3(8, 48), 256, 0, stream>>>(pbf, vbt, part, out);
}